// Round 5
// baseline (413.386 us; speedup 1.0000x reference)
//
#include <hip/hip_runtime.h>
#include <hip/hip_bf16.h>

// Performer FastAttention — MFMA bf16, register-resident softmax (swapped-S layout),
// two-pass query (approx-max pass kills register spills).
// B=4,H=16 -> BH=64; N=4096; D=E=64; M=256.

#define BH    64
#define NSEQ  4096
#define DD    64
#define MM    256
#define DN    0.35355339059327373f   // 64^-0.25
#define RATIO 0.0625f                 // 256^-0.5
#define EPS   1e-4f

// ws layout (float units): ctx_raw[bh][m][e], ksum_raw[bh][m], vsum_raw[bh][e], mg
#define CTX_OFF  0
#define KSUM_OFF (BH*MM*DD)
#define VSUM_OFF (KSUM_OFF + BH*MM)
#define MG_OFF   (VSUM_OFF + BH*DD)
#define WS_FLOATS (MG_OFF + 4)

typedef __attribute__((ext_vector_type(8)))  short bf16x8;
typedef __attribute__((ext_vector_type(16))) float f32x16;

#define MFMA(a,b,c) __builtin_amdgcn_mfma_f32_32x32x16_bf16((a),(b),(c),0,0,0)
#define PATROW(r,h) ((((r)&3) + 8*((r)>>2)) + 4*(h))

__device__ __forceinline__ unsigned short f2bf(float x) {
    unsigned u = __float_as_uint(x);
    return (unsigned short)((u + 0x7fffu + ((u >> 16) & 1u)) >> 16);
}
__device__ __forceinline__ void split8(const float* x, bf16x8& hv, bf16x8& lv) {
#pragma unroll
    for (int i = 0; i < 8; ++i) {
        unsigned short hb = f2bf(x[i]);
        float hf = __uint_as_float(((unsigned)hb) << 16);
        hv[i] = (short)hb;
        lv[i] = (short)f2bf(x[i] - hf);
    }
}
__device__ __forceinline__ unsigned ford(float f) {
    unsigned u = __float_as_uint(f);
    return (u & 0x80000000u) ? ~u : (u | 0x80000000u);
}
__device__ __forceinline__ float ford_inv(unsigned u) {
    return (u & 0x80000000u) ? __uint_as_float(u & 0x7fffffffu) : __uint_as_float(~u);
}
__device__ __forceinline__ unsigned pkbf(float lo, float hi) {
    union { __hip_bfloat162 b2; unsigned u; } cvt;
    cvt.b2 = __float22bfloat162_rn(make_float2(lo, hi));
    return cvt.u;
}
// C-layout tile (16 f32, rows = PATROW(r,h), col = l31) -> A-operand bf16 fragment
// for k-slice covering local rows BASE*2..BASE*2+15.
template<int BASE>
__device__ __forceinline__ bf16x8 repack8(const f32x16& a, int h) {
    unsigned X0 = pkbf(a[BASE+0], a[BASE+1]);
    unsigned X1 = pkbf(a[BASE+2], a[BASE+3]);
    unsigned Y0 = pkbf(a[BASE+4], a[BASE+5]);
    unsigned Y1 = pkbf(a[BASE+6], a[BASE+7]);
    unsigned tX0 = (unsigned)__shfl_xor((int)X0, 32);
    unsigned tX1 = (unsigned)__shfl_xor((int)X1, 32);
    unsigned tY0 = (unsigned)__shfl_xor((int)Y0, 32);
    unsigned tY1 = (unsigned)__shfl_xor((int)Y1, 32);
    union { unsigned w[4]; bf16x8 v; } r;
    r.w[0] = h ? tY0 : X0;
    r.w[1] = h ? tY1 : X1;
    r.w[2] = h ? Y0 : tX0;
    r.w[3] = h ? Y1 : tX1;
    return r.v;
}

// ============================ KEYS ============================
// grid 256 = bh(64) x seg(4); block 512 = 8 waves; 16 chunks x 64 k-rows.
__global__ __launch_bounds__(512, 2)
void keys_kernel(const float* __restrict__ kg, const float* __restrict__ vg,
                 const float* __restrict__ pg, float* __restrict__ ws)
{
    __shared__ __align__(16) short kfh[2][64*64];
    __shared__ __align__(16) short kfl[2][64*64];
    __shared__ __align__(16) short vT [2][64*72];
    __shared__ float diagl[2][64];
    __shared__ float ctxred[MM*DD];   // 64 KB
    __shared__ float vswr[8][64];

    const int tid  = threadIdx.x;
    const int wv   = tid >> 6;
    const int lane = tid & 63;
    const int l31  = lane & 31;
    const int h    = lane >> 5;
    const int bh   = blockIdx.x >> 2;
    const int seg  = blockIdx.x & 3;

    // proj B-fragments (col m = 32*wv + l31) straight from global
    bf16x8 pBh[4], pBl[4];
    {
        const int m = 32*wv + l31;
#pragma unroll
        for (int ks = 0; ks < 4; ++ks) {
            const int d0 = 16*ks + 8*h;
            float x[8];
            *(float4*)&x[0] = *(const float4*)(pg + m*64 + d0);
            *(float4*)&x[4] = *(const float4*)(pg + m*64 + d0 + 4);
            split8(x, pBh[ks], pBl[ks]);
        }
    }

    f32x16 cacc0, cacc1;
#pragma unroll
    for (int i = 0; i < 16; ++i) { cacc0[i] = 0.f; cacc1[i] = 0.f; }
    float ksacc = 0.f, mloc = -3e38f;
    float vsacc[8];
#pragma unroll
    for (int i = 0; i < 8; ++i) vsacc[i] = 0.f;

    auto stage = [&](int ch, int p) {
        const int n = tid >> 3, dg = tid & 7, d0 = dg*8;
        const size_t base = ((size_t)(bh*NSEQ + seg*1024 + ch*64 + n)) * DD;
        float x[8];
        *(float4*)&x[0] = *(const float4*)(kg + base + d0);
        *(float4*)&x[4] = *(const float4*)(kg + base + d0 + 4);
        float ss = 0.f;
#pragma unroll
        for (int i = 0; i < 8; ++i) { x[i] *= DN; ss += x[i]*x[i]; }
        ss += __shfl_xor(ss, 1); ss += __shfl_xor(ss, 2); ss += __shfl_xor(ss, 4);
        if (dg == 0) diagl[p][n] = 0.5f * ss;
        bf16x8 hv, lv; split8(x, hv, lv);
        const int ofs = dg*512 + ((n*8) ^ (dg*8));
        *(bf16x8*)&kfh[p][ofs] = hv;
        *(bf16x8*)&kfl[p][ofs] = lv;
        float y[8];
        *(float4*)&y[0] = *(const float4*)(vg + base + d0);
        *(float4*)&y[4] = *(const float4*)(vg + base + d0 + 4);
#pragma unroll
        for (int i = 0; i < 8; ++i) {
            vsacc[i] += y[i];
            vT[p][(d0+i)*72 + (n ^ (i<<3))] = (short)f2bf(y[i]);
        }
    };

    stage(0, 0);
    __syncthreads();
    int p = 0;
    for (int ch = 0; ch < 16; ++ch) {
        if (ch < 15) stage(ch+1, p^1);

        // ---- S = D[n][m]: 2 n-tiles, 3-term hi/lo ----
        f32x16 s0, s1;
#pragma unroll
        for (int i = 0; i < 16; ++i) { s0[i] = 0.f; s1[i] = 0.f; }
#pragma unroll
        for (int ks = 0; ks < 4; ++ks) {
            const int dg2 = ks*2 + h;
            const int ofs = dg2*512 + ((l31*8) ^ (dg2*8));
            bf16x8 a0h = *(const bf16x8*)&kfh[p][ofs];
            bf16x8 a0l = *(const bf16x8*)&kfl[p][ofs];
            bf16x8 a1h = *(const bf16x8*)&kfh[p][ofs + 256];
            bf16x8 a1l = *(const bf16x8*)&kfl[p][ofs + 256];
            s0 = MFMA(a0h, pBh[ks], s0);
            s1 = MFMA(a1h, pBh[ks], s1);
            s0 = MFMA(a0l, pBh[ks], s0);
            s1 = MFMA(a1l, pBh[ks], s1);
            s0 = MFMA(a0h, pBl[ks], s0);
            s1 = MFMA(a1h, pBl[ks], s1);
        }

        // ---- w = exp(S - diag), track global max & ksum, in regs ----
#pragma unroll
        for (int r = 0; r < 16; ++r) {
            const int n0 = PATROW(r, h);
            mloc = fmaxf(mloc, s0[r]);
            const float w0 = __expf(s0[r] - diagl[p][n0]);
            s0[r] = w0; ksacc += w0;
            mloc = fmaxf(mloc, s1[r]);
            const float w1 = __expf(s1[r] - diagl[p][32 + n0]);
            s1[r] = w1; ksacc += w1;
        }

        // ---- in-register repack to A[m][k=n] fragments ----
        bf16x8 wfr[4];
        wfr[0] = repack8<0>(s0, h);
        wfr[1] = repack8<8>(s0, h);
        wfr[2] = repack8<0>(s1, h);
        wfr[3] = repack8<8>(s1, h);

        // ---- ctx GEMM: D[m][e] += w * v ----
#pragma unroll
        for (int ks = 0; ks < 4; ++ks) {
            const int nb = 16*ks + 8*h;
            bf16x8 b0 = *(const bf16x8*)&vT[p][l31*72      + (nb ^ ((l31&7)<<3))];
            bf16x8 b1 = *(const bf16x8*)&vT[p][(l31+32)*72 + (nb ^ ((l31&7)<<3))];
            cacc0 = MFMA(wfr[ks], b0, cacc0);
            cacc1 = MFMA(wfr[ks], b1, cacc1);
        }
        __syncthreads();
        p ^= 1;
    }

    // ---- finals ----
    ksacc += __shfl_xor(ksacc, 32);
    if (h == 0) atomicAdd(&ws[KSUM_OFF + bh*MM + 32*wv + l31], ksacc);

#pragma unroll
    for (int m = 1; m <= 32; m <<= 1) mloc = fmaxf(mloc, __shfl_xor(mloc, m));
    if (lane == 0) atomicMax((unsigned*)&ws[MG_OFF], ford(mloc));

#pragma unroll
    for (int r = 0; r < 16; ++r) {
        const int m = 32*wv + PATROW(r, h);
        ctxred[m*64 + l31]      = cacc0[r];
        ctxred[m*64 + l31 + 32] = cacc1[r];
    }

#pragma unroll
    for (int i = 0; i < 8; ++i) {
        float v = vsacc[i];
        v += __shfl_xor(v, 8); v += __shfl_xor(v, 16); v += __shfl_xor(v, 32);
        vsacc[i] = v;
    }
    if (lane < 8) {
#pragma unroll
        for (int i = 0; i < 8; ++i) vswr[wv][lane*8 + i] = vsacc[i];
    }
    __syncthreads();

    for (int i = tid; i < MM*DD; i += 512)
        atomicAdd(&ws[CTX_OFF + bh*(MM*DD) + i], ctxred[i]);
    if (tid < 64) {
        float s = 0.f;
#pragma unroll
        for (int w = 0; w < 8; ++w) s += vswr[w][tid];
        atomicAdd(&ws[VSUM_OFF + bh*DD + tid], s);
    }
}

// ============================ QUERY ============================
// grid 256 = bh(64) x seg(4); block 512 = 8 waves; 4 chunks x 256 q-rows.
// Pass 1: hi-only S -> approximate per-row max (valid shift; num/den invariant
// to the shift up to the eps term, which has ~100x headroom).
// Pass 2: full 3-term S, one m-tile live at a time, fused exp->repack->num GEMM.
__global__ __launch_bounds__(512, 2)
void query_kernel(const float* __restrict__ qg, const float* __restrict__ pg,
                  const float* __restrict__ ws, float* __restrict__ out)
{
    __shared__ __align__(16) short pfh[MM*DD];      // proj hi, frag-grouped
    __shared__ __align__(16) short pfl[MM*DD];      // proj lo
    __shared__ __align__(16) short ctxb[32*96*8];   // (ksg*2+h) x ecol(0..95) x j

    const int tid  = threadIdx.x;
    const int wv   = tid >> 6;
    const int lane = tid & 63;
    const int l31  = lane & 31;
    const int h    = lane >> 5;
    const int bh   = blockIdx.x >> 2;
    const int seg  = blockIdx.x & 3;

    const float mg = ford_inv(*(const unsigned*)&ws[MG_OFF]);
    const float cs = RATIO * __expf(-mg);
    const float ce = RATIO * EPS;

    // proj staging -> frag-grouped LDS
    {
        const int m = tid >> 1, dh = tid & 1;
#pragma unroll
        for (int b = 0; b < 4; ++b) {
            const int d0 = dh*32 + b*8;
            float x[8];
            *(float4*)&x[0] = *(const float4*)(pg + m*64 + d0);
            *(float4*)&x[4] = *(const float4*)(pg + m*64 + d0 + 4);
            bf16x8 hv, lv; split8(x, hv, lv);
            const int g = ((m>>5)*4 + (d0>>4))*2 + ((d0>>3)&1);
            *(bf16x8*)&pfh[(g*32 + (m&31))*8] = hv;
            *(bf16x8*)&pfl[(g*32 + (m&31))*8] = lv;
        }
    }
    // ctx staging: fold cs/ce, bf16, frag-grouped (cols 0..63)
#pragma unroll
    for (int it = 0; it < 4; ++it) {
        const int gid = it*512 + tid;
        const int g = gid >> 6, e = gid & 63;
        const int mb = (g>>1)*16 + (g&1)*8;
        const float vs = ws[VSUM_OFF + bh*DD + e];
        union { short s[8]; bf16x8 v; } tmp;
#pragma unroll
        for (int j = 0; j < 8; ++j) {
            const float x = cs*ws[CTX_OFF + bh*(MM*DD) + (mb+j)*64 + e] + ce*vs;
            tmp.s[j] = (short)f2bf(x);
        }
        *(bf16x8*)&ctxb[(g*96 + e)*8] = tmp.v;
    }
    // ksum column (ecol 64) + zero columns (65..95)
    if (tid < 256) {
        const int m = tid;
        const float kt = cs*ws[KSUM_OFF + bh*MM + m] + ce*(float)NSEQ;
        const int g = (m>>4)*2 + ((m>>3)&1);
        ctxb[(g*96 + 64)*8 + (m&7)] = (short)f2bf(kt);
    }
    for (int idx = tid; idx < 32*31*8; idx += 512) {
        const int g = idx / 248, r2 = idx % 248;
        ctxb[(g*96 + 65)*8 + r2] = 0;
    }
    __syncthreads();

    for (int ch = 0; ch < 4; ++ch) {
        const int gn = bh*NSEQ + seg*1024 + ch*256 + wv*32 + l31;

        // q straight from global: B[k=d][col=n] fragments + per-lane diag
        bf16x8 qbh[4], qbl[4];
        float ss = 0.f;
#pragma unroll
        for (int ks = 0; ks < 4; ++ks) {
            const int d0 = 16*ks + 8*h;
            float x[8];
            *(float4*)&x[0] = *(const float4*)(qg + (size_t)gn*64 + d0);
            *(float4*)&x[4] = *(const float4*)(qg + (size_t)gn*64 + d0 + 4);
#pragma unroll
            for (int i = 0; i < 8; ++i) { x[i] *= DN; ss += x[i]*x[i]; }
            split8(x, qbh[ks], qbl[ks]);
        }
        const float diag = 0.5f * (ss + __shfl_xor(ss, 32));

        // ---- pass 1: approx per-row max (hi-only S), one tile live ----
        float mx = -3e38f;
#pragma unroll
        for (int mt = 0; mt < 8; ++mt) {
            f32x16 s;
#pragma unroll
            for (int i = 0; i < 16; ++i) s[i] = 0.f;
#pragma unroll
            for (int ks = 0; ks < 4; ++ks) {
                const int g = (mt*4 + ks)*2 + h;
                bf16x8 ah = *(const bf16x8*)&pfh[(g*32 + l31)*8];
                s = MFMA(ah, qbh[ks], s);
            }
#pragma unroll
            for (int i = 0; i < 16; ++i) mx = fmaxf(mx, s[i]);
        }
        mx = fmaxf(mx, __shfl_xor(mx, 32));
        const float c = diag + mx;

        // ---- pass 2: full S per m-tile -> exp -> repack -> num GEMM ----
        f32x16 n0, n1, n2;
#pragma unroll
        for (int i = 0; i < 16; ++i) { n0[i] = 0.f; n1[i] = 0.f; n2[i] = 0.f; }
#pragma unroll
        for (int mt = 0; mt < 8; ++mt) {
            f32x16 s;
#pragma unroll
            for (int i = 0; i < 16; ++i) s[i] = 0.f;
#pragma unroll
            for (int ks = 0; ks < 4; ++ks) {
                const int g = (mt*4 + ks)*2 + h;
                bf16x8 ah = *(const bf16x8*)&pfh[(g*32 + l31)*8];
                bf16x8 al = *(const bf16x8*)&pfl[(g*32 + l31)*8];
                s = MFMA(ah, qbh[ks], s);
                s = MFMA(al, qbh[ks], s);
                s = MFMA(ah, qbl[ks], s);
            }
#pragma unroll
            for (int r = 0; r < 16; ++r) s[r] = __expf(s[r] - c) + EPS;
            bf16x8 t0 = repack8<0>(s, h);
            bf16x8 t1 = repack8<8>(s, h);
            const int g0 = 4*mt + h, g1 = 4*mt + 2 + h;
            n0 = MFMA(t0, *(const bf16x8*)&ctxb[(g0*96 + l31)*8],      n0);
            n1 = MFMA(t0, *(const bf16x8*)&ctxb[(g0*96 + l31 + 32)*8], n1);
            n2 = MFMA(t0, *(const bf16x8*)&ctxb[(g0*96 + 64 + l31)*8], n2);
            n0 = MFMA(t1, *(const bf16x8*)&ctxb[(g1*96 + l31)*8],      n0);
            n1 = MFMA(t1, *(const bf16x8*)&ctxb[(g1*96 + l31 + 32)*8], n1);
            n2 = MFMA(t1, *(const bf16x8*)&ctxb[(g1*96 + 64 + l31)*8], n2);
        }

        // den = col 0 of tile 2 -> broadcast; out = num/den
#pragma unroll
        for (int r = 0; r < 16; ++r) {
            const float den = __shfl(n2[r], h ? 32 : 0);
            const float rdn = 1.0f / den;
            const int nn = PATROW(r, h);
            float* op = out + ((size_t)(bh*NSEQ + seg*1024 + ch*256 + wv*32 + nn))*64;
            op[l31]      = n0[r] * rdn;
            op[l31 + 32] = n1[r] * rdn;
        }
    }
}

extern "C" void kernel_launch(void* const* d_in, const int* in_sizes, int n_in,
                              void* d_out, int out_size, void* d_ws, size_t ws_size,
                              hipStream_t stream)
{
    const float* q = (const float*)d_in[0];
    const float* k = (const float*)d_in[1];
    const float* v = (const float*)d_in[2];
    const float* p = (const float*)d_in[3];
    float* ws  = (float*)d_ws;
    float* out = (float*)d_out;

    (void)hipMemsetAsync(d_ws, 0, (size_t)WS_FLOATS * sizeof(float), stream);
    keys_kernel<<<dim3(256), dim3(512), 0, stream>>>(k, v, p, ws);
    query_kernel<<<dim3(256), dim3(512), 0, stream>>>(q, p, ws, out);
}

// Round 6
// 139.807 us; speedup vs baseline: 2.9568x; 2.9568x over previous
//
#include <hip/hip_runtime.h>
#include <hip/hip_bf16.h>

// Performer FastAttention — MFMA bf16, single-pass query with unshifted exp +
// eps-correction (no per-row-shift needed; max folded into eps term only).
// proj used as bf16 (hi) consistently in both kernels; k/q kept hi/lo.
// B=4,H=16 -> BH=64; N=4096; D=E=64; M=256.

#define BH    64
#define NSEQ  4096
#define DD    64
#define MM    256
#define DN    0.35355339059327373f   // 64^-0.25
#define RATIO 0.0625f                 // 256^-0.5
#define EPS   1e-4f

// ws layout (float units): ctx_raw[bh][m][e], ksum_raw[bh][m], vsum_raw[bh][e], mg
#define CTX_OFF  0
#define KSUM_OFF (BH*MM*DD)
#define VSUM_OFF (KSUM_OFF + BH*MM)
#define MG_OFF   (VSUM_OFF + BH*DD)
#define WS_FLOATS (MG_OFF + 4)

typedef __attribute__((ext_vector_type(8)))  short bf16x8;
typedef __attribute__((ext_vector_type(16))) float f32x16;

#define MFMA(a,b,c) __builtin_amdgcn_mfma_f32_32x32x16_bf16((a),(b),(c),0,0,0)
#define PATROW(r,h) ((((r)&3) + 8*((r)>>2)) + 4*(h))

__device__ __forceinline__ unsigned short f2bf(float x) {
    unsigned u = __float_as_uint(x);
    return (unsigned short)((u + 0x7fffu + ((u >> 16) & 1u)) >> 16);
}
__device__ __forceinline__ void split8(const float* x, bf16x8& hv, bf16x8& lv) {
#pragma unroll
    for (int i = 0; i < 8; ++i) {
        unsigned short hb = f2bf(x[i]);
        float hf = __uint_as_float(((unsigned)hb) << 16);
        hv[i] = (short)hb;
        lv[i] = (short)f2bf(x[i] - hf);
    }
}
__device__ __forceinline__ bf16x8 hi8(const float* x) {
    union { short s[8]; bf16x8 v; } r;
#pragma unroll
    for (int i = 0; i < 8; ++i) r.s[i] = (short)f2bf(x[i]);
    return r.v;
}
__device__ __forceinline__ unsigned ford(float f) {
    unsigned u = __float_as_uint(f);
    return (u & 0x80000000u) ? ~u : (u | 0x80000000u);
}
__device__ __forceinline__ float ford_inv(unsigned u) {
    return (u & 0x80000000u) ? __uint_as_float(u & 0x7fffffffu) : __uint_as_float(~u);
}
__device__ __forceinline__ unsigned pkbf(float lo, float hi) {
    union { __hip_bfloat162 b2; unsigned u; } cvt;
    cvt.b2 = __float22bfloat162_rn(make_float2(lo, hi));
    return cvt.u;
}
// C-layout tile (16 f32, rows = PATROW(r,h), col = l31) -> A-operand bf16 fragment
// for k-slice covering local rows BASE*2..BASE*2+15.
template<int BASE>
__device__ __forceinline__ bf16x8 repack8(const f32x16& a, int h) {
    unsigned X0 = pkbf(a[BASE+0], a[BASE+1]);
    unsigned X1 = pkbf(a[BASE+2], a[BASE+3]);
    unsigned Y0 = pkbf(a[BASE+4], a[BASE+5]);
    unsigned Y1 = pkbf(a[BASE+6], a[BASE+7]);
    unsigned tX0 = (unsigned)__shfl_xor((int)X0, 32);
    unsigned tX1 = (unsigned)__shfl_xor((int)X1, 32);
    unsigned tY0 = (unsigned)__shfl_xor((int)Y0, 32);
    unsigned tY1 = (unsigned)__shfl_xor((int)Y1, 32);
    union { unsigned w[4]; bf16x8 v; } r;
    r.w[0] = h ? tY0 : X0;
    r.w[1] = h ? tY1 : X1;
    r.w[2] = h ? Y0 : tX0;
    r.w[3] = h ? Y1 : tX1;
    return r.v;
}

// ============================ KEYS ============================
// grid 256 = bh(64) x seg(4); block 512 = 8 waves; 16 chunks x 64 k-rows.
// S (2-term: kh*Ph + kl*Ph) -> w=exp(S-diag) in regs -> repack -> ctx GEMM.
__global__ __launch_bounds__(512, 2)
void keys_kernel(const float* __restrict__ kg, const float* __restrict__ vg,
                 const float* __restrict__ pg, float* __restrict__ ws)
{
    __shared__ __align__(16) short kfh[2][64*64];
    __shared__ __align__(16) short kfl[2][64*64];
    __shared__ __align__(16) short vT [2][64*72];
    __shared__ float diagl[2][64];
    __shared__ float ctxred[MM*DD];   // 64 KB
    __shared__ float vswr[8][64];

    const int tid  = threadIdx.x;
    const int wv   = tid >> 6;
    const int lane = tid & 63;
    const int l31  = lane & 31;
    const int h    = lane >> 5;
    const int bh   = blockIdx.x >> 2;
    const int seg  = blockIdx.x & 3;

    // proj B-fragments (col m = 32*wv + l31), bf16-hi only
    bf16x8 pBh[4];
    {
        const int m = 32*wv + l31;
#pragma unroll
        for (int ks = 0; ks < 4; ++ks) {
            const int d0 = 16*ks + 8*h;
            float x[8];
            *(float4*)&x[0] = *(const float4*)(pg + m*64 + d0);
            *(float4*)&x[4] = *(const float4*)(pg + m*64 + d0 + 4);
            pBh[ks] = hi8(x);
        }
    }

    f32x16 cacc0, cacc1;
#pragma unroll
    for (int i = 0; i < 16; ++i) { cacc0[i] = 0.f; cacc1[i] = 0.f; }
    float ksacc = 0.f, mloc = -3e38f;
    float vsacc[8];
#pragma unroll
    for (int i = 0; i < 8; ++i) vsacc[i] = 0.f;

    auto stage = [&](int ch, int p) {
        const int n = tid >> 3, dg = tid & 7, d0 = dg*8;
        const size_t base = ((size_t)(bh*NSEQ + seg*1024 + ch*64 + n)) * DD;
        float x[8];
        *(float4*)&x[0] = *(const float4*)(kg + base + d0);
        *(float4*)&x[4] = *(const float4*)(kg + base + d0 + 4);
        float ss = 0.f;
#pragma unroll
        for (int i = 0; i < 8; ++i) { x[i] *= DN; ss += x[i]*x[i]; }
        ss += __shfl_xor(ss, 1); ss += __shfl_xor(ss, 2); ss += __shfl_xor(ss, 4);
        if (dg == 0) diagl[p][n] = 0.5f * ss;
        bf16x8 hv, lv; split8(x, hv, lv);
        const int ofs = dg*512 + ((n*8) ^ (dg*8));
        *(bf16x8*)&kfh[p][ofs] = hv;
        *(bf16x8*)&kfl[p][ofs] = lv;
        float y[8];
        *(float4*)&y[0] = *(const float4*)(vg + base + d0);
        *(float4*)&y[4] = *(const float4*)(vg + base + d0 + 4);
#pragma unroll
        for (int i = 0; i < 8; ++i) {
            vsacc[i] += y[i];
            vT[p][(d0+i)*72 + (n ^ (i<<3))] = (short)f2bf(y[i]);
        }
    };

    stage(0, 0);
    __syncthreads();
    int p = 0;
    for (int ch = 0; ch < 16; ++ch) {
        if (ch < 15) stage(ch+1, p^1);

        // ---- S = D[n][m]: 2 n-tiles, 2-term (k hi+lo, proj hi) ----
        f32x16 s0, s1;
#pragma unroll
        for (int i = 0; i < 16; ++i) { s0[i] = 0.f; s1[i] = 0.f; }
#pragma unroll
        for (int ks = 0; ks < 4; ++ks) {
            const int dg2 = ks*2 + h;
            const int ofs = dg2*512 + ((l31*8) ^ (dg2*8));
            bf16x8 a0h = *(const bf16x8*)&kfh[p][ofs];
            bf16x8 a0l = *(const bf16x8*)&kfl[p][ofs];
            bf16x8 a1h = *(const bf16x8*)&kfh[p][ofs + 256];
            bf16x8 a1l = *(const bf16x8*)&kfl[p][ofs + 256];
            s0 = MFMA(a0h, pBh[ks], s0);
            s1 = MFMA(a1h, pBh[ks], s1);
            s0 = MFMA(a0l, pBh[ks], s0);
            s1 = MFMA(a1l, pBh[ks], s1);
        }

        // ---- w = exp(S - diag), track global max & ksum ----
#pragma unroll
        for (int r = 0; r < 16; ++r) {
            const int n0 = PATROW(r, h);
            mloc = fmaxf(mloc, s0[r]);
            const float w0 = __expf(s0[r] - diagl[p][n0]);
            s0[r] = w0; ksacc += w0;
            mloc = fmaxf(mloc, s1[r]);
            const float w1 = __expf(s1[r] - diagl[p][32 + n0]);
            s1[r] = w1; ksacc += w1;
        }

        // ---- in-register repack to A[m][k=n] fragments ----
        bf16x8 wfr[4];
        wfr[0] = repack8<0>(s0, h);
        wfr[1] = repack8<8>(s0, h);
        wfr[2] = repack8<0>(s1, h);
        wfr[3] = repack8<8>(s1, h);

        // ---- ctx GEMM: D[m][e] += w * v ----
#pragma unroll
        for (int ks = 0; ks < 4; ++ks) {
            const int nb = 16*ks + 8*h;
            bf16x8 b0 = *(const bf16x8*)&vT[p][l31*72      + (nb ^ ((l31&7)<<3))];
            bf16x8 b1 = *(const bf16x8*)&vT[p][(l31+32)*72 + (nb ^ ((l31&7)<<3))];
            cacc0 = MFMA(wfr[ks], b0, cacc0);
            cacc1 = MFMA(wfr[ks], b1, cacc1);
        }
        __syncthreads();
        p ^= 1;
    }

    // ---- finals ----
    ksacc += __shfl_xor(ksacc, 32);
    if (h == 0) atomicAdd(&ws[KSUM_OFF + bh*MM + 32*wv + l31], ksacc);

#pragma unroll
    for (int m = 1; m <= 32; m <<= 1) mloc = fmaxf(mloc, __shfl_xor(mloc, m));
    if (lane == 0) atomicMax((unsigned*)&ws[MG_OFF], ford(mloc));

#pragma unroll
    for (int r = 0; r < 16; ++r) {
        const int m = 32*wv + PATROW(r, h);
        ctxred[m*64 + l31]      = cacc0[r];
        ctxred[m*64 + l31 + 32] = cacc1[r];
    }

#pragma unroll
    for (int i = 0; i < 8; ++i) {
        float v = vsacc[i];
        v += __shfl_xor(v, 8); v += __shfl_xor(v, 16); v += __shfl_xor(v, 32);
        vsacc[i] = v;
    }
    if (lane < 8) {
#pragma unroll
        for (int i = 0; i < 8; ++i) vswr[wv][lane*8 + i] = vsacc[i];
    }
    __syncthreads();

    for (int i = tid; i < MM*DD; i += 512)
        atomicAdd(&ws[CTX_OFF + bh*(MM*DD) + i], ctxred[i]);
    if (tid < 64) {
        float s = 0.f;
#pragma unroll
        for (int w = 0; w < 8; ++w) s += vswr[w][tid];
        atomicAdd(&ws[VSUM_OFF + bh*DD + tid], s);
    }
}

// ============================ QUERY ============================
// grid 256 = bh(64) x seg(4); block 512 = 8 waves; 4 chunks x 256 q-rows.
// Single pass: u = exp(kd - diag) unshifted; per-row max only scales the
// eps-correction: num += eps*e^m*ctxsum, den = sum(u*ksum) + eps*e^m*ksumsum.
__global__ __launch_bounds__(512, 2)
void query_kernel(const float* __restrict__ qg, const float* __restrict__ pg,
                  const float* __restrict__ ws, float* __restrict__ out)
{
    __shared__ __align__(16) short pfh[MM*DD];      // proj hi, frag-grouped (32 KB)
    __shared__ __align__(16) short ctxb[32*64*8];   // (ksg*2+h) x ecol x j (32 KB)
    __shared__ float ksuml[MM];
    __shared__ float ctxsuml[DD];
    __shared__ float ksumsuml;
    __shared__ float epsl[8][32];
    __shared__ float denl[8][32];

    const int tid  = threadIdx.x;
    const int wv   = tid >> 6;
    const int lane = tid & 63;
    const int l31  = lane & 31;
    const int h    = lane >> 5;
    const int bh   = blockIdx.x >> 2;
    const int seg  = blockIdx.x & 3;

    const float mg = ford_inv(*(const unsigned*)&ws[MG_OFF]);
    const float cs = RATIO * __expf(-mg);
    const float ce = RATIO * EPS;

    if (tid < DD) ctxsuml[tid] = 0.f;
    if (tid == 0) ksumsuml = 0.f;
    __syncthreads();

    // proj staging (hi only) -> frag-grouped LDS
    {
        const int m = tid >> 1, dh = tid & 1;
#pragma unroll
        for (int b = 0; b < 4; ++b) {
            const int d0 = dh*32 + b*8;
            float x[8];
            *(float4*)&x[0] = *(const float4*)(pg + m*64 + d0);
            *(float4*)&x[4] = *(const float4*)(pg + m*64 + d0 + 4);
            const int g = ((m>>5)*4 + (d0>>4))*2 + ((d0>>3)&1);
            *(bf16x8*)&pfh[(g*32 + (m&31))*8] = hi8(x);
        }
    }
    // ctx staging: fold cs/ce, bf16, frag-grouped; accumulate ctxsum
#pragma unroll
    for (int it = 0; it < 4; ++it) {
        const int gid = it*512 + tid;
        const int g = gid >> 6, e = gid & 63;
        const int mb = (g>>1)*16 + (g&1)*8;
        const float vs = ws[VSUM_OFF + bh*DD + e];
        float part = 0.f;
        union { short s[8]; bf16x8 v; } tmp;
#pragma unroll
        for (int j = 0; j < 8; ++j) {
            const float x = cs*ws[CTX_OFF + bh*(MM*DD) + (mb+j)*64 + e] + ce*vs;
            part += x;
            tmp.s[j] = (short)f2bf(x);
        }
        *(bf16x8*)&ctxb[(g*64 + e)*8] = tmp.v;
        atomicAdd(&ctxsuml[e], part);
    }
    // ksum (f32) + ksumsum
    if (tid < 256) {
        const float kt = cs*ws[KSUM_OFF + bh*MM + tid] + ce*(float)NSEQ;
        ksuml[tid] = kt;
        atomicAdd(&ksumsuml, kt);
    }
    __syncthreads();

    const float cs0 = ctxsuml[l31];
    const float cs1 = ctxsuml[l31 + 32];
    const float kss = ksumsuml;

    for (int ch = 0; ch < 4; ++ch) {
        const int rown = seg*1024 + ch*256 + wv*32;
        const size_t gn = (size_t)(bh*NSEQ + rown + l31);

        // q straight from global: B[k=d][col=n] fragments + per-lane diag
        bf16x8 qbh[4], qbl[4];
        float ss = 0.f;
#pragma unroll
        for (int ks = 0; ks < 4; ++ks) {
            const int d0 = 16*ks + 8*h;
            float x[8];
            *(float4*)&x[0] = *(const float4*)(qg + gn*64 + d0);
            *(float4*)&x[4] = *(const float4*)(qg + gn*64 + d0 + 4);
#pragma unroll
            for (int i = 0; i < 8; ++i) { x[i] *= DN; ss += x[i]*x[i]; }
            split8(x, qbh[ks], qbl[ks]);
        }
        const float diag = 0.5f * (ss + __shfl_xor(ss, 32));

        // ---- fused: S tile -> u=exp(S-diag) -> max/den -> repack -> num GEMM ----
        f32x16 n0, n1;
#pragma unroll
        for (int i = 0; i < 16; ++i) { n0[i] = 0.f; n1[i] = 0.f; }
        float den = 0.f, mx = -3e38f;
#pragma unroll
        for (int mt = 0; mt < 8; ++mt) {
            f32x16 s;
#pragma unroll
            for (int i = 0; i < 16; ++i) s[i] = 0.f;
#pragma unroll
            for (int ks = 0; ks < 4; ++ks) {
                const int g = (mt*4 + ks)*2 + h;
                bf16x8 ah = *(const bf16x8*)&pfh[(g*32 + l31)*8];
                s = MFMA(ah, qbh[ks], s);
                s = MFMA(ah, qbl[ks], s);
            }
#pragma unroll
            for (int r = 0; r < 16; ++r) mx = fmaxf(mx, s[r]);
#pragma unroll
            for (int r = 0; r < 16; ++r) {
                const float u = __expf(s[r] - diag);
                s[r] = u;
                den = fmaf(u, ksuml[mt*32 + PATROW(r, h)], den);
            }
            bf16x8 t0 = repack8<0>(s, h);
            bf16x8 t1 = repack8<8>(s, h);
            const int g0 = 4*mt + h, g1 = 4*mt + 2 + h;
            n0 = MFMA(t0, *(const bf16x8*)&ctxb[(g0*64 + l31)*8],      n0);
            n1 = MFMA(t0, *(const bf16x8*)&ctxb[(g0*64 + l31 + 32)*8], n1);
            n0 = MFMA(t1, *(const bf16x8*)&ctxb[(g1*64 + l31)*8],      n0);
            n1 = MFMA(t1, *(const bf16x8*)&ctxb[(g1*64 + l31 + 32)*8], n1);
        }

        // combine h-halves for this lane's own row (col l31)
        mx  = fmaxf(mx, __shfl_xor(mx, 32));
        den += __shfl_xor(den, 32);
        const float epsp = EPS * __expf(mx);
        const float denf = den + epsp * kss;
        if (h == 0) { epsl[wv][l31] = epsp; denl[wv][l31] = denf; }
        asm volatile("s_waitcnt lgkmcnt(0)" ::: "memory");

        // out = (num + eps*e^m*ctxsum) / den   (rows nn from per-wave LDS)
#pragma unroll
        for (int r = 0; r < 16; ++r) {
            const int nn = PATROW(r, h);
            const float e1  = epsl[wv][nn];
            const float rdn = 1.0f / denl[wv][nn];
            float* op = out + ((size_t)(bh*NSEQ + rown + nn))*64;
            op[l31]      = (n0[r] + e1*cs0) * rdn;
            op[l31 + 32] = (n1[r] + e1*cs1) * rdn;
        }
    }
}

extern "C" void kernel_launch(void* const* d_in, const int* in_sizes, int n_in,
                              void* d_out, int out_size, void* d_ws, size_t ws_size,
                              hipStream_t stream)
{
    const float* q = (const float*)d_in[0];
    const float* k = (const float*)d_in[1];
    const float* v = (const float*)d_in[2];
    const float* p = (const float*)d_in[3];
    float* ws  = (float*)d_ws;
    float* out = (float*)d_out;

    (void)hipMemsetAsync(d_ws, 0, (size_t)WS_FLOATS * sizeof(float), stream);
    keys_kernel<<<dim3(256), dim3(512), 0, stream>>>(k, v, p, ws);
    query_kernel<<<dim3(256), dim3(512), 0, stream>>>(q, p, ws, out);
}